// Round 1
// baseline (257.133 us; speedup 1.0000x reference)
//
#include <hip/hip_runtime.h>

// CustomPuzzleLoss: loss1 = mean|p - t|, loss2 = 0.1 * dup_count/B over 5x5
// grids (rows+cols, exact float equality, "seen earlier" semantics),
// +1000 if any p outside [0.5, 5.5]. Output: single float scalar.
//
// R13: counters show the timed iteration = 2x 400MiB poison fills (~61us,
// 86% HBM peak, uncontrollable) + main (<60.5us, below top-5 cutoff) +
// final (~4-6us serial). R12's coverage theory was neutral -> main is not
// prefetch-bound. Remaining levers: (a) remove the puzzle_final dispatch
// (launch gap + 1-block latency-bound kernel) by fusing the reduction into
// the last-arriving block (ticket + device-scope fences, deterministic
// order identical to old final); (b) ping-pong A/B tile buffers instead of
// `cur = nxt` struct copy: kills 26 v_mov/tile and the vmcnt(0) full drain,
// doubles in-flight depth to 2 tiles/wave. All-nt loads (R11 A/B).

#define BLOCK 256
#define WPB 4                     // waves per block
#define TILE 1600                 // floats per wave-tile = 64 grids * 25
#define NBLOCKS 768               // 3 blocks/CU; 12 waves/CU; 5.33 tiles/wave

typedef float v4f __attribute__((ext_vector_type(4)));
typedef int   v4i __attribute__((ext_vector_type(4)));

struct TileRegs {
    v4f p[6];
    v4i t[6];
    float ptl;
    int   ttl;
};

__device__ __forceinline__ void load_tile(const float* __restrict__ preds,
                                          const int* __restrict__ tgts,
                                          long long t, int lane, TileRegs& r) {
    const v4f* __restrict__ p4 = (const v4f*)(preds + t * TILE);
    const v4i* __restrict__ t4 = (const v4i*)(tgts  + t * TILE);
    #pragma unroll
    for (int k = 0; k < 6; ++k) r.p[k] = __builtin_nontemporal_load(&p4[lane + 64 * k]);
    #pragma unroll
    for (int k = 0; k < 6; ++k) r.t[k] = __builtin_nontemporal_load(&t4[lane + 64 * k]);
    r.ptl = __builtin_nontemporal_load(&preds[t * TILE + 1536 + lane]);
    r.ttl = __builtin_nontemporal_load(&tgts [t * TILE + 1536 + lane]);
}

// dup count for one 5x5 grid (pointer into LDS; compiler folds the loads)
__device__ __forceinline__ int grid_dups(const float* __restrict__ p) {
    int ldup = 0;
    #pragma unroll
    for (int r = 0; r < 5; ++r) {           // rows
        const float a = p[r*5+0], b = p[r*5+1], c = p[r*5+2],
                    d = p[r*5+3], e = p[r*5+4];
        ldup += (int)(b == a);
        ldup += (int)((c == a) | (c == b));
        ldup += (int)((d == a) | (d == b) | (d == c));
        ldup += (int)((e == a) | (e == b) | (e == c) | (e == d));
    }
    #pragma unroll
    for (int q = 0; q < 5; ++q) {           // cols
        const float a = p[q+0], b = p[q+5], c = p[q+10],
                    d = p[q+15], e = p[q+20];
        ldup += (int)(b == a);
        ldup += (int)((c == a) | (c == b));
        ldup += (int)((d == a) | (d == b) | (d == c));
        ldup += (int)((e == a) | (e == b) | (e == c) | (e == d));
    }
    return ldup;
}

__device__ __forceinline__ void compute_tile(const TileRegs& r,
                                             float* __restrict__ wp,
                                             v4f* __restrict__ wp4,
                                             int lane, float& lsum, int& ldup,
                                             float& mn, float& mx) {
    #pragma unroll
    for (int k = 0; k < 6; ++k) {
        wp4[lane + 64 * k] = r.p[k];
        lsum += fabsf(r.p[k].x - (float)r.t[k].x);
        lsum += fabsf(r.p[k].y - (float)r.t[k].y);
        lsum += fabsf(r.p[k].z - (float)r.t[k].z);
        lsum += fabsf(r.p[k].w - (float)r.t[k].w);
        mn = fminf(mn, fminf(fminf(r.p[k].x, r.p[k].y), fminf(r.p[k].z, r.p[k].w)));
        mx = fmaxf(mx, fmaxf(fmaxf(r.p[k].x, r.p[k].y), fmaxf(r.p[k].z, r.p[k].w)));
    }
    wp[1536 + lane] = r.ptl;
    lsum += fabsf(r.ptl - (float)r.ttl);
    mn = fminf(mn, r.ptl);
    mx = fmaxf(mx, r.ptl);

    // dup pass: lane owns grid `lane` = 25 consecutive floats in the wave's
    // own LDS slice (stride 25 = 2-way bank aliasing, free). Wave reads only
    // its own writes -> compiler-managed lgkmcnt ordering, no barrier.
    ldup += grid_dups(wp + lane * 25);
}

__global__ __launch_bounds__(BLOCK, 1) void puzzle_main(
    const float* __restrict__ preds, const int* __restrict__ tgts,
    long long n_total, long long batch,
    float* __restrict__ blk_sum, int* __restrict__ blk_dup,
    int* __restrict__ blk_oob,
    unsigned* __restrict__ ticket, float* __restrict__ out)
{
    __shared__ float lds_p[WPB * TILE];     // 25600 B: one 6.4KB slice/wave
    __shared__ float s_sum[WPB];
    __shared__ int   s_dup[WPB];
    __shared__ int   s_oob[WPB];
    __shared__ int   s_last;
    __shared__ double f_sum[WPB];
    __shared__ int    f_dup[WPB];
    __shared__ int    f_oob[WPB];

    const int tid  = threadIdx.x;
    const int lane = tid & 63;
    const int wv   = tid >> 6;

    const long long total_tiles = n_total / TILE;
    const int total_waves = gridDim.x * WPB;
    const int gwave = blockIdx.x * WPB + wv;

    float* __restrict__ wp = &lds_p[wv * TILE];
    v4f* __restrict__ wp4 = reinterpret_cast<v4f*>(wp);

    float lsum = 0.0f;
    int   ldup = 0;
    float mn =  1e30f;
    float mx = -1e30f;

    // --- ping-pong 2-deep pipeline over this wave's ~5.33 tiles ---
    const long long stride = total_waves;
    long long tA = gwave;
    if (tA < total_tiles) {
        TileRegs A, B;
        long long tB = tA + stride;
        load_tile(preds, tgts, tA, lane, A);
        __builtin_amdgcn_sched_barrier(0);
        if (tB < total_tiles) {
            load_tile(preds, tgts, tB, lane, B);
            __builtin_amdgcn_sched_barrier(0);
        }
        for (;;) {
            compute_tile(A, wp, wp4, lane, lsum, ldup, mn, mx);
            tA += 2 * stride;
            if (tA < total_tiles) {
                load_tile(preds, tgts, tA, lane, A);
                __builtin_amdgcn_sched_barrier(0);
            }
            if (tB >= total_tiles) break;
            compute_tile(B, wp, wp4, lane, lsum, ldup, mn, mx);
            tB += 2 * stride;
            if (tB < total_tiles) {
                load_tile(preds, tgts, tB, lane, B);
                __builtin_amdgcn_sched_barrier(0);
            }
            if (tA >= total_tiles) break;
        }
    }

    // ragged tail (n % TILE != 0; n always a multiple of 25): direct global.
    const long long rem = n_total - total_tiles * TILE;
    if (rem > 0 && gwave == total_waves - 1) {
        const int ngrids = (int)(rem / 25);
        if (lane < ngrids) {
            const float* sp = preds + total_tiles * TILE + (long long)lane * 25;
            const int*   st = tgts  + total_tiles * TILE + (long long)lane * 25;
            float q[25];
            #pragma unroll
            for (int j = 0; j < 25; ++j) q[j] = sp[j];
            #pragma unroll
            for (int j = 0; j < 25; ++j) {
                lsum += fabsf(q[j] - (float)st[j]);
                mn = fminf(mn, q[j]);
                mx = fmaxf(mx, q[j]);
            }
            ldup += grid_dups(q);
        }
    }

    // wave reduction
    #pragma unroll
    for (int off = 32; off > 0; off >>= 1) {
        lsum += __shfl_down(lsum, off, 64);
        ldup += __shfl_down(ldup, off, 64);
        mn = fminf(mn, __shfl_down(mn, off, 64));
        mx = fmaxf(mx, __shfl_down(mx, off, 64));
    }
    if (lane == 0) {
        s_sum[wv] = lsum;
        s_dup[wv] = ldup;
        s_oob[wv] = (int)((mn < 0.5f) | (mx > 5.5f));
    }
    __syncthreads();
    if (tid == 0) {
        float bs = 0.0f; int bd = 0, bo = 0;
        #pragma unroll
        for (int w = 0; w < WPB; ++w) { bs += s_sum[w]; bd += s_dup[w]; bo |= s_oob[w]; }
        blk_sum[blockIdx.x] = bs;
        blk_dup[blockIdx.x] = bd;
        blk_oob[blockIdx.x] = bo;
        __threadfence();   // release: partials visible device-wide before ticket
        const unsigned old = __hip_atomic_fetch_add(ticket, 1u, __ATOMIC_ACQ_REL,
                                                    __HIP_MEMORY_SCOPE_AGENT);
        s_last = (old == (unsigned)(gridDim.x - 1));
    }
    __syncthreads();

    // --- fused finisher: only the last-arriving block runs this.
    // Same 256-thread strided + shuffle reduction order as the old
    // puzzle_final kernel -> bit-identical result.
    if (s_last) {
        __threadfence();   // acquire side for every participating thread
        const int nblocks = (int)gridDim.x;
        double fsum = 0.0;
        int fdup = 0, foob = 0;
        for (int i = tid; i < nblocks; i += BLOCK) {
            fsum += (double)__hip_atomic_load(&blk_sum[i], __ATOMIC_RELAXED,
                                              __HIP_MEMORY_SCOPE_AGENT);
            fdup += __hip_atomic_load(&blk_dup[i], __ATOMIC_RELAXED,
                                      __HIP_MEMORY_SCOPE_AGENT);
            foob |= __hip_atomic_load(&blk_oob[i], __ATOMIC_RELAXED,
                                      __HIP_MEMORY_SCOPE_AGENT);
        }
        #pragma unroll
        for (int off = 32; off > 0; off >>= 1) {
            fsum += __shfl_down(fsum, off, 64);
            fdup += __shfl_down(fdup, off, 64);
            foob |= __shfl_down(foob, off, 64);
        }
        if (lane == 0) { f_sum[wv] = fsum; f_dup[wv] = fdup; f_oob[wv] = foob; }
        __syncthreads();
        if (tid == 0) {
            double bs = 0.0; int bd = 0, bo = 0;
            #pragma unroll
            for (int w = 0; w < WPB; ++w) { bs += f_sum[w]; bd += f_dup[w]; bo |= f_oob[w]; }
            const float loss1 = (float)(bs / (double)n_total);
            const float loss2 = (float)((double)bd * 0.1 / (double)batch);
            out[0] = loss1 + loss2 + (bo ? 1000.0f : 0.0f);
        }
    }
}

extern "C" void kernel_launch(void* const* d_in, const int* in_sizes, int n_in,
                              void* d_out, int out_size, void* d_ws, size_t ws_size,
                              hipStream_t stream) {
    const float* preds = (const float*)d_in[0];
    const int*   tgts  = (const int*)d_in[1];
    float* out = (float*)d_out;

    const long long n = (long long)in_sizes[0];
    const long long batch = n / 25;

    // workspace layout: [u32 ticket | pad to 16B | float sums | int dups | int oobs]
    unsigned* ticket = (unsigned*)d_ws;
    float* blk_sum = (float*)((char*)d_ws + 16);
    int*   blk_dup = (int*)((char*)d_ws + 16 + 4 * NBLOCKS);
    int*   blk_oob = (int*)((char*)d_ws + 16 + 8 * NBLOCKS);

    // zero only the ticket (workspace is poisoned by the harness each iter)
    hipMemsetAsync(ticket, 0, sizeof(unsigned), stream);

    puzzle_main<<<NBLOCKS, BLOCK, 0, stream>>>(preds, tgts, n, batch,
                                               blk_sum, blk_dup, blk_oob,
                                               ticket, out);
}

// Round 2
// 205.084 us; speedup vs baseline: 1.2538x; 1.2538x over previous
//
#include <hip/hip_runtime.h>

// CustomPuzzleLoss: loss1 = mean|p - t|, loss2 = 0.1 * dup_count/B over 5x5
// grids (rows+cols, exact float equality, "seen earlier" semantics),
// +1000 if any p outside [0.5, 5.5]. Output: single float scalar.
//
// R14: R13 regressed (202->257) from two self-inflicted wounds:
// (a) ping-pong loop made in-loop re-loads CONDITIONAL -> waitcnt merge at
//     loop header forced vmcnt(0) before every compute, serializing each
//     tile to full memory latency (counters: HBM 15%, VALU 10%, occ 15%);
// (b) __threadfence + ACQ_REL ticket per block -> 768x buffer_wbl2/inv on
//     non-coherent XCD L2s, slowing main AND the following harness fills.
// Fix: restore R12's exact main loop (unconditional in-loop prefetch,
// cur=nxt copy). Keep the fused finisher but make it fence-free: relaxed
// agent-scope atomic stores (SC-bit write-through, bypass L2) + explicit
// s_waitcnt vmcnt(0) + relaxed ticket fetch_add; reader uses relaxed
// agent-scope atomic loads (bypass stale poison lines in reader L2).
// No wbl2/inv anywhere. Reduction order bit-identical to old puzzle_final.

#define BLOCK 256
#define WPB 4                     // waves per block
#define TILE 1600                 // floats per wave-tile = 64 grids * 25
#define NBLOCKS 768               // 3 blocks/CU; 12 waves/CU; 5.33 tiles/wave

typedef float v4f __attribute__((ext_vector_type(4)));
typedef int   v4i __attribute__((ext_vector_type(4)));

struct TileRegs {
    v4f p[6];
    v4i t[6];
    float ptl;
    int   ttl;
};

__device__ __forceinline__ void load_tile(const float* __restrict__ preds,
                                          const int* __restrict__ tgts,
                                          long long t, int lane, TileRegs& r) {
    const v4f* __restrict__ p4 = (const v4f*)(preds + t * TILE);
    const v4i* __restrict__ t4 = (const v4i*)(tgts  + t * TILE);
    #pragma unroll
    for (int k = 0; k < 6; ++k) r.p[k] = __builtin_nontemporal_load(&p4[lane + 64 * k]);
    #pragma unroll
    for (int k = 0; k < 6; ++k) r.t[k] = __builtin_nontemporal_load(&t4[lane + 64 * k]);
    r.ptl = __builtin_nontemporal_load(&preds[t * TILE + 1536 + lane]);
    r.ttl = __builtin_nontemporal_load(&tgts [t * TILE + 1536 + lane]);
}

// dup count for one 5x5 grid (pointer into LDS; compiler folds the loads)
__device__ __forceinline__ int grid_dups(const float* __restrict__ p) {
    int ldup = 0;
    #pragma unroll
    for (int r = 0; r < 5; ++r) {           // rows
        const float a = p[r*5+0], b = p[r*5+1], c = p[r*5+2],
                    d = p[r*5+3], e = p[r*5+4];
        ldup += (int)(b == a);
        ldup += (int)((c == a) | (c == b));
        ldup += (int)((d == a) | (d == b) | (d == c));
        ldup += (int)((e == a) | (e == b) | (e == c) | (e == d));
    }
    #pragma unroll
    for (int q = 0; q < 5; ++q) {           // cols
        const float a = p[q+0], b = p[q+5], c = p[q+10],
                    d = p[q+15], e = p[q+20];
        ldup += (int)(b == a);
        ldup += (int)((c == a) | (c == b));
        ldup += (int)((d == a) | (d == b) | (d == c));
        ldup += (int)((e == a) | (e == b) | (e == c) | (e == d));
    }
    return ldup;
}

__device__ __forceinline__ void compute_tile(const TileRegs& r,
                                             float* __restrict__ wp,
                                             v4f* __restrict__ wp4,
                                             int lane, float& lsum, int& ldup,
                                             float& mn, float& mx) {
    #pragma unroll
    for (int k = 0; k < 6; ++k) {
        wp4[lane + 64 * k] = r.p[k];
        lsum += fabsf(r.p[k].x - (float)r.t[k].x);
        lsum += fabsf(r.p[k].y - (float)r.t[k].y);
        lsum += fabsf(r.p[k].z - (float)r.t[k].z);
        lsum += fabsf(r.p[k].w - (float)r.t[k].w);
        mn = fminf(mn, fminf(fminf(r.p[k].x, r.p[k].y), fminf(r.p[k].z, r.p[k].w)));
        mx = fmaxf(mx, fmaxf(fmaxf(r.p[k].x, r.p[k].y), fmaxf(r.p[k].z, r.p[k].w)));
    }
    wp[1536 + lane] = r.ptl;
    lsum += fabsf(r.ptl - (float)r.ttl);
    mn = fminf(mn, r.ptl);
    mx = fmaxf(mx, r.ptl);

    // dup pass: lane owns grid `lane` = 25 consecutive floats in the wave's
    // own LDS slice (stride 25 = 2-way bank aliasing, free). Wave reads only
    // its own writes -> compiler-managed lgkmcnt ordering, no barrier.
    ldup += grid_dups(wp + lane * 25);
}

__global__ __launch_bounds__(BLOCK, 1) void puzzle_main(
    const float* __restrict__ preds, const int* __restrict__ tgts,
    long long n_total, long long batch,
    float* __restrict__ blk_sum, int* __restrict__ blk_dup,
    int* __restrict__ blk_oob,
    unsigned* __restrict__ ticket, float* __restrict__ out)
{
    __shared__ float lds_p[WPB * TILE];     // 25600 B: one 6.4KB slice/wave
    __shared__ float s_sum[WPB];
    __shared__ int   s_dup[WPB];
    __shared__ int   s_oob[WPB];
    __shared__ int   s_last;
    __shared__ double f_sum[WPB];
    __shared__ int    f_dup[WPB];
    __shared__ int    f_oob[WPB];

    const int tid  = threadIdx.x;
    const int lane = tid & 63;
    const int wv   = tid >> 6;

    const long long total_tiles = n_total / TILE;
    const int total_waves = gridDim.x * WPB;
    const int gwave = blockIdx.x * WPB + wv;

    float* __restrict__ wp = &lds_p[wv * TILE];
    v4f* __restrict__ wp4 = reinterpret_cast<v4f*>(wp);

    float lsum = 0.0f;
    int   ldup = 0;
    float mn =  1e30f;
    float mx = -1e30f;

    // --- R12's proven 2-stage software pipeline (in-loop load UNconditional
    // -> clean vmcnt(14)-style waits, prefetch stays in flight) ---
    long long t0 = gwave;
    if (t0 < total_tiles) {
        TileRegs cur, nxt;
        load_tile(preds, tgts, t0, lane, cur);
        __builtin_amdgcn_sched_barrier(0);
        for (long long tn = t0 + total_waves; tn < total_tiles; tn += total_waves) {
            load_tile(preds, tgts, tn, lane, nxt);       // prefetch t+1
            __builtin_amdgcn_sched_barrier(0);           // pin: loads stay above
            compute_tile(cur, wp, wp4, lane, lsum, ldup, mn, mx);
            cur = nxt;                                   // register copy
        }
        compute_tile(cur, wp, wp4, lane, lsum, ldup, mn, mx);
    }

    // ragged tail (n % TILE != 0; n always a multiple of 25): direct global.
    const long long rem = n_total - total_tiles * TILE;
    if (rem > 0 && gwave == total_waves - 1) {
        const int ngrids = (int)(rem / 25);
        if (lane < ngrids) {
            const float* sp = preds + total_tiles * TILE + (long long)lane * 25;
            const int*   st = tgts  + total_tiles * TILE + (long long)lane * 25;
            float q[25];
            #pragma unroll
            for (int j = 0; j < 25; ++j) q[j] = sp[j];
            #pragma unroll
            for (int j = 0; j < 25; ++j) {
                lsum += fabsf(q[j] - (float)st[j]);
                mn = fminf(mn, q[j]);
                mx = fmaxf(mx, q[j]);
            }
            ldup += grid_dups(q);
        }
    }

    // wave reduction
    #pragma unroll
    for (int off = 32; off > 0; off >>= 1) {
        lsum += __shfl_down(lsum, off, 64);
        ldup += __shfl_down(ldup, off, 64);
        mn = fminf(mn, __shfl_down(mn, off, 64));
        mx = fmaxf(mx, __shfl_down(mx, off, 64));
    }
    if (lane == 0) {
        s_sum[wv] = lsum;
        s_dup[wv] = ldup;
        s_oob[wv] = (int)((mn < 0.5f) | (mx > 5.5f));
    }
    __syncthreads();
    if (tid == 0) {
        float bs = 0.0f; int bd = 0, bo = 0;
        #pragma unroll
        for (int w = 0; w < WPB; ++w) { bs += s_sum[w]; bd += s_dup[w]; bo |= s_oob[w]; }
        // Fence-free release: relaxed agent-scope atomic stores compile to
        // SC-bit write-through stores (bypass non-coherent XCD L2, land at
        // the agent coherence point). vmcnt(0) retires them there BEFORE the
        // ticket increment is issued. No buffer_wbl2 emitted.
        __hip_atomic_store(&blk_sum[blockIdx.x], bs, __ATOMIC_RELAXED,
                           __HIP_MEMORY_SCOPE_AGENT);
        __hip_atomic_store(&blk_dup[blockIdx.x], bd, __ATOMIC_RELAXED,
                           __HIP_MEMORY_SCOPE_AGENT);
        __hip_atomic_store(&blk_oob[blockIdx.x], bo, __ATOMIC_RELAXED,
                           __HIP_MEMORY_SCOPE_AGENT);
        asm volatile("s_waitcnt vmcnt(0)" ::: "memory");
        const unsigned old = __hip_atomic_fetch_add(ticket, 1u, __ATOMIC_RELAXED,
                                                    __HIP_MEMORY_SCOPE_AGENT);
        s_last = (old == (unsigned)(gridDim.x - 1));
    }
    __syncthreads();

    // --- fused finisher: only the last-arriving block runs this.
    // Relaxed agent-scope atomic loads bypass this XCD's L2 (which may hold
    // stale poison lines from the harness fill) and read the coherent point.
    // Same 256-thread strided + shuffle reduction order as the old
    // puzzle_final kernel -> bit-identical result. No buffer_inv emitted.
    if (s_last) {
        const int nblocks = (int)gridDim.x;
        double fsum = 0.0;
        int fdup = 0, foob = 0;
        for (int i = tid; i < nblocks; i += BLOCK) {
            fsum += (double)__hip_atomic_load(&blk_sum[i], __ATOMIC_RELAXED,
                                              __HIP_MEMORY_SCOPE_AGENT);
            fdup += __hip_atomic_load(&blk_dup[i], __ATOMIC_RELAXED,
                                      __HIP_MEMORY_SCOPE_AGENT);
            foob |= __hip_atomic_load(&blk_oob[i], __ATOMIC_RELAXED,
                                      __HIP_MEMORY_SCOPE_AGENT);
        }
        #pragma unroll
        for (int off = 32; off > 0; off >>= 1) {
            fsum += __shfl_down(fsum, off, 64);
            fdup += __shfl_down(fdup, off, 64);
            foob |= __shfl_down(foob, off, 64);
        }
        if (lane == 0) { f_sum[wv] = fsum; f_dup[wv] = fdup; f_oob[wv] = foob; }
        __syncthreads();
        if (tid == 0) {
            double bs = 0.0; int bd = 0, bo = 0;
            #pragma unroll
            for (int w = 0; w < WPB; ++w) { bs += f_sum[w]; bd += f_dup[w]; bo |= f_oob[w]; }
            const float loss1 = (float)(bs / (double)n_total);
            const float loss2 = (float)((double)bd * 0.1 / (double)batch);
            out[0] = loss1 + loss2 + (bo ? 1000.0f : 0.0f);
        }
    }
}

extern "C" void kernel_launch(void* const* d_in, const int* in_sizes, int n_in,
                              void* d_out, int out_size, void* d_ws, size_t ws_size,
                              hipStream_t stream) {
    const float* preds = (const float*)d_in[0];
    const int*   tgts  = (const int*)d_in[1];
    float* out = (float*)d_out;

    const long long n = (long long)in_sizes[0];
    const long long batch = n / 25;

    // workspace layout: [u32 ticket | pad to 16B | float sums | int dups | int oobs]
    unsigned* ticket = (unsigned*)d_ws;
    float* blk_sum = (float*)((char*)d_ws + 16);
    int*   blk_dup = (int*)((char*)d_ws + 16 + 4 * NBLOCKS);
    int*   blk_oob = (int*)((char*)d_ws + 16 + 8 * NBLOCKS);

    // zero only the ticket (workspace is poisoned by the harness each iter)
    hipMemsetAsync(ticket, 0, sizeof(unsigned), stream);

    puzzle_main<<<NBLOCKS, BLOCK, 0, stream>>>(preds, tgts, n, batch,
                                               blk_sum, blk_dup, blk_oob,
                                               ticket, out);
}

// Round 4
// 203.165 us; speedup vs baseline: 1.2656x; 1.0094x over previous
//
#include <hip/hip_runtime.h>

// CustomPuzzleLoss: loss1 = mean|p - t|, loss2 = 0.1 * dup_count/B over 5x5
// grids (rows+cols, exact float equality, "seen earlier" semantics),
// +1000 if any p outside [0.5, 5.5]. Output: single float scalar.
//
// R16 = R15 resubmitted verbatim (R15 bench was an infra failure: container
// acquisition failed twice; kernel never ran).
//
// R15: championship revert to R12's exact two-kernel structure (202.1 us).
// Session findings pinned here:
//  - Timed region = 2x 400MiB harness poison fills (~122us @ 6.8-6.9 TB/s,
//    WRITE roofline, uncontrollable) + main (~60us) + final+gaps (~15-20us).
//  - main is at the READ roofline: 210 MB read-only @ ~3.5 TB/s. Read-only
//    streams cap at ~half the write BW on MI355X (m13's "6.3 TB/s" is a
//    copy counting both directions; fills prove writes alone hit 6.9).
//    Occupancy sweep 512->768 blocks was exactly neutral -> per-CU
//    miss-tracking cap, not latency-hiding deficit. Do NOT re-attempt
//    pipeline-depth / occupancy levers here.
//  - R13 lesson: in-loop prefetch loads must be UNCONDITIONAL, else the
//    waitcnt merge at the loop header forces vmcnt(0) per tile (86us).
//  - R13 lesson: __threadfence / ACQ_REL atomics per block emit
//    buffer_wbl2/inv on non-coherent XCD L2s and poison the harness fills.
//  - R14 lesson: fusing the finisher via ticket+memset == two-kernel within
//    noise (205 vs 202): saved final dispatch ~= added memset dispatch.
//    Keep the simpler two-kernel form.
//  - All-nt loads beat plain (R11 A/B): plain loads pollute L3 and slow the
//    harness's allocate path.

#define BLOCK 256
#define WPB 4                     // waves per block
#define TILE 1600                 // floats per wave-tile = 64 grids * 25
#define NBLOCKS 768               // 3 blocks/CU; 12 waves/CU; 5.33 tiles/wave

typedef float v4f __attribute__((ext_vector_type(4)));
typedef int   v4i __attribute__((ext_vector_type(4)));

struct TileRegs {
    v4f p[6];
    v4i t[6];
    float ptl;
    int   ttl;
};

__device__ __forceinline__ void load_tile(const float* __restrict__ preds,
                                          const int* __restrict__ tgts,
                                          long long t, int lane, TileRegs& r) {
    const v4f* __restrict__ p4 = (const v4f*)(preds + t * TILE);
    const v4i* __restrict__ t4 = (const v4i*)(tgts  + t * TILE);
    #pragma unroll
    for (int k = 0; k < 6; ++k) r.p[k] = __builtin_nontemporal_load(&p4[lane + 64 * k]);
    #pragma unroll
    for (int k = 0; k < 6; ++k) r.t[k] = __builtin_nontemporal_load(&t4[lane + 64 * k]);
    r.ptl = __builtin_nontemporal_load(&preds[t * TILE + 1536 + lane]);
    r.ttl = __builtin_nontemporal_load(&tgts [t * TILE + 1536 + lane]);
}

// dup count for one 5x5 grid (pointer into LDS; compiler folds the loads)
__device__ __forceinline__ int grid_dups(const float* __restrict__ p) {
    int ldup = 0;
    #pragma unroll
    for (int r = 0; r < 5; ++r) {           // rows
        const float a = p[r*5+0], b = p[r*5+1], c = p[r*5+2],
                    d = p[r*5+3], e = p[r*5+4];
        ldup += (int)(b == a);
        ldup += (int)((c == a) | (c == b));
        ldup += (int)((d == a) | (d == b) | (d == c));
        ldup += (int)((e == a) | (e == b) | (e == c) | (e == d));
    }
    #pragma unroll
    for (int q = 0; q < 5; ++q) {           // cols
        const float a = p[q+0], b = p[q+5], c = p[q+10],
                    d = p[q+15], e = p[q+20];
        ldup += (int)(b == a);
        ldup += (int)((c == a) | (c == b));
        ldup += (int)((d == a) | (d == b) | (d == c));
        ldup += (int)((e == a) | (e == b) | (e == c) | (e == d));
    }
    return ldup;
}

__device__ __forceinline__ void compute_tile(const TileRegs& r,
                                             float* __restrict__ wp,
                                             v4f* __restrict__ wp4,
                                             int lane, float& lsum, int& ldup,
                                             float& mn, float& mx) {
    #pragma unroll
    for (int k = 0; k < 6; ++k) {
        wp4[lane + 64 * k] = r.p[k];
        lsum += fabsf(r.p[k].x - (float)r.t[k].x);
        lsum += fabsf(r.p[k].y - (float)r.t[k].y);
        lsum += fabsf(r.p[k].z - (float)r.t[k].z);
        lsum += fabsf(r.p[k].w - (float)r.t[k].w);
        mn = fminf(mn, fminf(fminf(r.p[k].x, r.p[k].y), fminf(r.p[k].z, r.p[k].w)));
        mx = fmaxf(mx, fmaxf(fmaxf(r.p[k].x, r.p[k].y), fmaxf(r.p[k].z, r.p[k].w)));
    }
    wp[1536 + lane] = r.ptl;
    lsum += fabsf(r.ptl - (float)r.ttl);
    mn = fminf(mn, r.ptl);
    mx = fmaxf(mx, r.ptl);

    // dup pass: lane owns grid `lane` = 25 consecutive floats in the wave's
    // own LDS slice (stride 25 = 2-way bank aliasing, free). Wave reads only
    // its own writes -> compiler-managed lgkmcnt ordering, no barrier.
    ldup += grid_dups(wp + lane * 25);
}

__global__ __launch_bounds__(BLOCK, 1) void puzzle_main(
    const float* __restrict__ preds, const int* __restrict__ tgts,
    long long n_total,
    float* __restrict__ blk_sum, int* __restrict__ blk_dup,
    int* __restrict__ blk_oob)
{
    __shared__ float lds_p[WPB * TILE];     // 25600 B: one 6.4KB slice/wave
    __shared__ float s_sum[WPB];
    __shared__ int   s_dup[WPB];
    __shared__ int   s_oob[WPB];

    const int tid  = threadIdx.x;
    const int lane = tid & 63;
    const int wv   = tid >> 6;

    const long long total_tiles = n_total / TILE;
    const int total_waves = gridDim.x * WPB;
    const int gwave = blockIdx.x * WPB + wv;

    float* __restrict__ wp = &lds_p[wv * TILE];
    v4f* __restrict__ wp4 = reinterpret_cast<v4f*>(wp);

    float lsum = 0.0f;
    int   ldup = 0;
    float mn =  1e30f;
    float mx = -1e30f;

    // --- 2-stage software pipeline over this wave's ~5.33 tiles ---
    // In-loop load is UNCONDITIONAL (R13 lesson: conditional re-loads force
    // vmcnt(0) at the loop-header waitcnt merge, serializing every tile).
    long long t0 = gwave;
    if (t0 < total_tiles) {
        TileRegs cur, nxt;
        load_tile(preds, tgts, t0, lane, cur);
        __builtin_amdgcn_sched_barrier(0);
        for (long long tn = t0 + total_waves; tn < total_tiles; tn += total_waves) {
            load_tile(preds, tgts, tn, lane, nxt);       // prefetch t+1
            __builtin_amdgcn_sched_barrier(0);           // pin: loads stay above
            compute_tile(cur, wp, wp4, lane, lsum, ldup, mn, mx);
            cur = nxt;                                   // register copy
        }
        compute_tile(cur, wp, wp4, lane, lsum, ldup, mn, mx);
    }

    // ragged tail (n % TILE != 0; n always a multiple of 25): direct global.
    const long long rem = n_total - total_tiles * TILE;
    if (rem > 0 && gwave == total_waves - 1) {
        const int ngrids = (int)(rem / 25);
        if (lane < ngrids) {
            const float* sp = preds + total_tiles * TILE + (long long)lane * 25;
            const int*   st = tgts  + total_tiles * TILE + (long long)lane * 25;
            float q[25];
            #pragma unroll
            for (int j = 0; j < 25; ++j) q[j] = sp[j];
            #pragma unroll
            for (int j = 0; j < 25; ++j) {
                lsum += fabsf(q[j] - (float)st[j]);
                mn = fminf(mn, q[j]);
                mx = fmaxf(mx, q[j]);
            }
            ldup += grid_dups(q);
        }
    }

    // wave reduction
    #pragma unroll
    for (int off = 32; off > 0; off >>= 1) {
        lsum += __shfl_down(lsum, off, 64);
        ldup += __shfl_down(ldup, off, 64);
        mn = fminf(mn, __shfl_down(mn, off, 64));
        mx = fmaxf(mx, __shfl_down(mx, off, 64));
    }
    if (lane == 0) {
        s_sum[wv] = lsum;
        s_dup[wv] = ldup;
        s_oob[wv] = (int)((mn < 0.5f) | (mx > 5.5f));
    }
    __syncthreads();
    if (tid == 0) {
        float bs = 0.0f; int bd = 0, bo = 0;
        #pragma unroll
        for (int w = 0; w < WPB; ++w) { bs += s_sum[w]; bd += s_dup[w]; bo |= s_oob[w]; }
        blk_sum[blockIdx.x] = bs;
        blk_dup[blockIdx.x] = bd;
        blk_oob[blockIdx.x] = bo;
    }
}

#define FBLOCK 256
#define FNWAVES (FBLOCK / 64)

__global__ __launch_bounds__(FBLOCK) void puzzle_final(
    const float* __restrict__ blk_sum, const int* __restrict__ blk_dup,
    const int* __restrict__ blk_oob, int nblocks,
    long long n_total, long long batch, float* __restrict__ out)
{
    __shared__ double s_sum[FNWAVES];
    __shared__ int    s_dup[FNWAVES];
    __shared__ int    s_oob[FNWAVES];

    double lsum = 0.0;
    int ldup = 0, loob = 0;
    for (int i = threadIdx.x; i < nblocks; i += FBLOCK) {
        lsum += (double)blk_sum[i];
        ldup += blk_dup[i];
        loob |= blk_oob[i];
    }
    #pragma unroll
    for (int off = 32; off > 0; off >>= 1) {
        lsum += __shfl_down(lsum, off, 64);
        ldup += __shfl_down(ldup, off, 64);
        loob |= __shfl_down(loob, off, 64);
    }
    const int wave = threadIdx.x >> 6;
    if ((threadIdx.x & 63) == 0) { s_sum[wave] = lsum; s_dup[wave] = ldup; s_oob[wave] = loob; }
    __syncthreads();
    if (threadIdx.x == 0) {
        double bs = 0.0; int bd = 0, bo = 0;
        #pragma unroll
        for (int w = 0; w < FNWAVES; ++w) { bs += s_sum[w]; bd += s_dup[w]; bo |= s_oob[w]; }
        const float loss1 = (float)(bs / (double)n_total);
        const float loss2 = (float)((double)bd * 0.1 / (double)batch);
        out[0] = loss1 + loss2 + (bo ? 1000.0f : 0.0f);
    }
}

extern "C" void kernel_launch(void* const* d_in, const int* in_sizes, int n_in,
                              void* d_out, int out_size, void* d_ws, size_t ws_size,
                              hipStream_t stream) {
    const float* preds = (const float*)d_in[0];
    const int*   tgts  = (const int*)d_in[1];
    float* out = (float*)d_out;

    const long long n = (long long)in_sizes[0];
    const long long batch = n / 25;

    // workspace layout: [float sums | int dups | int oobs], each NBLOCKS long
    float* blk_sum = (float*)d_ws;
    int*   blk_dup = (int*)(blk_sum + NBLOCKS);
    int*   blk_oob = (int*)(blk_dup + NBLOCKS);

    puzzle_main<<<NBLOCKS, BLOCK, 0, stream>>>(preds, tgts, n,
                                               blk_sum, blk_dup, blk_oob);
    puzzle_final<<<1, FBLOCK, 0, stream>>>(blk_sum, blk_dup, blk_oob,
                                           NBLOCKS, n, batch, out);
}